// Round 13
// baseline (7032.843 us; speedup 1.0000x reference)
//
#include <hip/hip_runtime.h>

// VQ-VAE vector quantizer forward (fp32).
// inputs: (32,256,32,32) f32 -> flat rows N=32768 x D=256
// embedding: (D=256, K=1024) f32, cluster_size: (1024,) f32
// outputs (flat f32): quantized[N*D], vq_loss, perplexity, code_usage, indices[N] (as float)

constexpr int DIM = 256;   // embedding dim
constexpr int NK  = 1024;  // number of codes
constexpr int RR  = 16;    // input rows per block (8 per wave row-group)

// async 16B global->LDS. HW dest = wave-uniform base + lane*16.
#define GLL16(GSRC, LDST)                                                      \
  __builtin_amdgcn_global_load_lds(                                            \
      (const __attribute__((address_space(1))) void*)(GSRC),                   \
      (__attribute__((address_space(3))) void*)(LDST), 16, 0, 0)

// ---------------------------------------------------------------- enorm (0.5*|e_k|^2)
__global__ __launch_bounds__(256) void enorm_kernel(
    const float* __restrict__ emb, float* __restrict__ enorm) {
  int k = blockIdx.x * 256 + threadIdx.x;
  float s = 0.f;
  for (int d = 0; d < DIM; ++d) {
    float e = emb[(size_t)d * NK + k];
    s = fmaf(e, e, s);
  }
  enorm[k] = 0.5f * s;                   // argmin(|e|^2-2x.e) == argmin(0.5|e|^2-x.e)
}

// ---------------------------------------------------------------- argmin
// 512 threads = 8 waves; 16 rows/block. Waves 0-3 (half=0): rows 0-7;
// waves 4-7 (half=1): rows 8-15. Thread owns codes c0..c0+3, c0=4*(tid&255)
// -> each 4-wave group covers all 1024 codes for its rows. ONE shared es
// tile serves both row-groups (halves L2 emb traffic vs R11): thread stages
// 2 dims/group (half 0 -> dims 4G,4G+1; half 1 -> dims 4G+2,4G+3); cross-
// wave reads -> one __syncthreads per group (its implicit vmcnt(0) drain is
// the pipeline wait: stage(g+1) issued BEFORE compute(g), landed by the
// barrier). x: 8 rows in SGPR ping-pong per wave (R11-proven codegen).
#define STAGE(G, P)                                                            \
  { const float* _s = emb + (size_t)(4 * (G) + 2 * half) * NK + c0;            \
    GLL16(_s,      &es[(P)][2 * half][c0]);                                    \
    GLL16(_s + NK, &es[(P)][2 * half + 1][c0]); }

#define XLOAD(XA, G)                                                           \
  _Pragma("unroll")                                                            \
  for (int r = 0; r < 8; ++r)                                                  \
    XA[r] = *(const float4*)&xg[r * DIM + 4 * (G)];

#define COMPUTE(PAR, XA)                                                       \
  { const float4 e0 = *(const float4*)&es[(PAR)][0][c0];                       \
    const float4 e1 = *(const float4*)&es[(PAR)][1][c0];                       \
    const float4 e2 = *(const float4*)&es[(PAR)][2][c0];                       \
    const float4 e3 = *(const float4*)&es[(PAR)][3][c0];                       \
    _Pragma("unroll")                                                          \
    for (int r = 0; r < 8; ++r) {                                              \
      const float4 xv = XA[r];                                                 \
      acc[r][0] = fmaf(xv.x, e0.x, fmaf(xv.y, e1.x, fmaf(xv.z, e2.x, fmaf(xv.w, e3.x, acc[r][0])))); \
      acc[r][1] = fmaf(xv.x, e0.y, fmaf(xv.y, e1.y, fmaf(xv.z, e2.y, fmaf(xv.w, e3.y, acc[r][1])))); \
      acc[r][2] = fmaf(xv.x, e0.z, fmaf(xv.y, e1.z, fmaf(xv.z, e2.z, fmaf(xv.w, e3.z, acc[r][2])))); \
      acc[r][3] = fmaf(xv.x, e0.w, fmaf(xv.y, e1.w, fmaf(xv.z, e2.w, fmaf(xv.w, e3.w, acc[r][3])))); \
    } }

__global__ __launch_bounds__(512, 8) void argmin_kernel(
    const float* __restrict__ x, const float* __restrict__ emb,
    const float* __restrict__ enorm, int* __restrict__ idx_out,
    float* __restrict__ idx_out_f) {
  __shared__ float es[2][4][NK];   // 32 KB double-buffered e-tile (shared by all 8 waves)
  __shared__ float red_v[8][8];
  __shared__ int   red_i[8][8];

  const int tid  = threadIdx.x;
  const int lane = tid & 63;
  const int wv   = tid >> 6;          // 0..7
  const int half = tid >> 8;          // 0: rows 0-7, 1: rows 8-15
  const int c0   = 4 * (tid & 255);   // this thread's code quad
  const float* xg = x + (size_t)blockIdx.x * (RR * DIM) + (size_t)half * 8 * DIM;

  STAGE(0, 0)
  __syncthreads();   // buf0 resident (implicit vmcnt(0) drain)

  float4 xA[8], xB[8];   // block-uniform per wave -> SGPR ping-pong
  XLOAD(xA, 0)

  float acc[8][4];
  #pragma unroll
  for (int r = 0; r < 8; ++r)
    #pragma unroll
    for (int j = 0; j < 4; ++j) acc[r][j] = 0.f;

  #pragma unroll 1
  for (int gg = 0; gg < 32; ++gg) {
    const int g0 = 2 * gg;
    const int g1 = g0 + 1;
    // even group: stage g1 into buf1, compute buf0; barrier lands g1
    STAGE(g1, 1)
    XLOAD(xB, g1)
    COMPUTE(0, xA)
    __syncthreads();
    // odd group: stage g1+1 into buf0 (free since barrier), compute buf1
    if (gg < 31) {
      STAGE(g1 + 1, 0)
      XLOAD(xA, g1 + 1)
    }
    COMPUTE(1, xB)
    __syncthreads();
  }

  const float4 en = *(const float4*)(enorm + c0);   // 0.5*|e|^2

  for (int r = 0; r < 8; ++r) {
    // score = 0.5|e|^2 - x.e ; strict < keeps lowest index on ties
    float bv = en.x - acc[r][0];
    int   bi = c0;
    { float v = en.y - acc[r][1]; if (v < bv) { bv = v; bi = c0 + 1; } }
    { float v = en.z - acc[r][2]; if (v < bv) { bv = v; bi = c0 + 2; } }
    { float v = en.w - acc[r][3]; if (v < bv) { bv = v; bi = c0 + 3; } }
    for (int off = 32; off > 0; off >>= 1) {
      float ov = __shfl_xor(bv, off);
      int   oi = __shfl_xor(bi, off);
      if (ov < bv || (ov == bv && oi < bi)) { bv = ov; bi = oi; }
    }
    if (lane == 0) { red_v[wv][r] = bv; red_i[wv][r] = bi; }
  }
  __syncthreads();

  if (tid < RR) {
    const int row = tid & 7;
    const int grp = tid >> 3;          // 0: waves 0-3, 1: waves 4-7
    float bv = red_v[4 * grp][row];
    int   bi = red_i[4 * grp][row];
    #pragma unroll
    for (int w = 1; w < 4; ++w) {
      float v = red_v[4 * grp + w][row]; int i2 = red_i[4 * grp + w][row];
      if (v < bv || (v == bv && i2 < bi)) { bv = v; bi = i2; }
    }
    const int n = blockIdx.x * RR + tid;
    idx_out[n]   = bi;
    idx_out_f[n] = (float)bi;
  }
}

// ---------------------------------------------------------------- gather + loss partials
__global__ __launch_bounds__(256) void gather_loss_kernel(
    const float* __restrict__ x, const float* __restrict__ emb,
    const int* __restrict__ idx, float* __restrict__ out_q,
    float* __restrict__ partial) {
  const int tid = threadIdx.x;
  const size_t base = (size_t)blockIdx.x * 2048;
  float local = 0.f;
  #pragma unroll
  for (int h = 0; h < 2; ++h) {
    const size_t g = base + (size_t)h * 1024 + (size_t)tid * 4;
    const int n = (int)(g >> 8);
    const int d = (int)(g & 255);
    const int k = idx[n];
    const float* ep = emb + (size_t)d * NK + k;
    float4 q;
    q.x = ep[0]; q.y = ep[NK]; q.z = ep[2 * NK]; q.w = ep[3 * NK];
    const float4 xv = *(const float4*)(x + g);
    *(float4*)(out_q + g) = q;
    const float dx = q.x - xv.x, dy = q.y - xv.y, dz = q.z - xv.z, dw = q.w - xv.w;
    local = fmaf(dx, dx, local);
    local = fmaf(dy, dy, local);
    local = fmaf(dz, dz, local);
    local = fmaf(dw, dw, local);
  }
  for (int off = 32; off > 0; off >>= 1) local += __shfl_down(local, off);
  __shared__ float wsum[4];
  if ((tid & 63) == 0) wsum[tid >> 6] = local;
  __syncthreads();
  if (tid == 0) partial[blockIdx.x] = (wsum[0] + wsum[1]) + (wsum[2] + wsum[3]);
}

// ---------------------------------------------------------------- finalize scalars
__global__ __launch_bounds__(1024) void finalize_kernel(
    const float* __restrict__ partial, int np,
    const float* __restrict__ cs, float* __restrict__ out_s,
    float inv_count) {
  __shared__ float sd[1024];
  const int tid = threadIdx.x;

  float s = 0.f;
  for (int i = tid; i < np; i += 1024) s += partial[i];
  sd[tid] = s; __syncthreads();
  for (int st = 512; st > 0; st >>= 1) {
    if (tid < st) sd[tid] += sd[tid + st];
    __syncthreads();
  }
  const float total_sq = sd[0];
  __syncthreads();

  const float c = cs[tid];
  sd[tid] = c; __syncthreads();
  for (int st = 512; st > 0; st >>= 1) {
    if (tid < st) sd[tid] += sd[tid + st];
    __syncthreads();
  }
  const float S = sd[0];
  __syncthreads();

  const float p = c / (S + 1e-5f);
  sd[tid] = p * logf(p + 1e-5f);
  __syncthreads();
  for (int st = 512; st > 0; st >>= 1) {
    if (tid < st) sd[tid] += sd[tid + st];
    __syncthreads();
  }
  const float T = sd[0];
  __syncthreads();

  sd[tid] = (c > 1e-5f) ? 1.f : 0.f;
  __syncthreads();
  for (int st = 512; st > 0; st >>= 1) {
    if (tid < st) sd[tid] += sd[tid + st];
    __syncthreads();
  }
  const float U = sd[0];

  if (tid == 0) {
    out_s[0] = 1.25f * total_sq * inv_count;  // e_latent + 0.25*q_latent
    out_s[1] = expf(-T);                      // perplexity
    out_s[2] = U * (1.f / 1024.f);            // code usage rate
  }
}

// ---------------------------------------------------------------- launch
extern "C" void kernel_launch(void* const* d_in, const int* in_sizes, int n_in,
                              void* d_out, int out_size, void* d_ws, size_t ws_size,
                              hipStream_t stream) {
  const float* x   = (const float*)d_in[0];
  const float* emb = (const float*)d_in[1];
  const float* cs  = (const float*)d_in[2];
  float* out = (float*)d_out;

  const int N = in_sizes[0] / DIM;          // 32768
  const size_t ND = (size_t)N * DIM;        // 8388608

  float* enorm   = (float*)d_ws;                                           // 4 KB
  int*   idxw    = (int*)((char*)d_ws + NK * sizeof(float));               // 128 KB
  float* partial = (float*)((char*)d_ws + NK * sizeof(float) + (size_t)N * sizeof(int)); // 16 KB

  const int nGather = (int)(ND / 2048);     // 4096

  enorm_kernel<<<NK / 256, 256, 0, stream>>>(emb, enorm);
  argmin_kernel<<<N / RR, 512, 0, stream>>>(x, emb, enorm, idxw, out + ND + 3);
  gather_loss_kernel<<<nGather, 256, 0, stream>>>(x, emb, idxw, out, partial);
  finalize_kernel<<<1, 1024, 0, stream>>>(partial, nGather, cs, out + ND,
                                          1.0f / (float)ND);
}